// Round 20
// baseline (57.795 us; speedup 1.0000x reference)
//
#include <hip/hip_runtime.h>

#define BB   16
#define HH   74
#define WW   74
#define DD   768
#define NHh  8
#define NOo  16
#define NREL 117
#define NKQ  8
#define KCH  96                      // channels per kq slice
#define MAXBH 15
#define ABSTRIDE (384 * 512)

#define FMA4(A, s, W) \
    A.x = fmaf((s), (W).x, A.x); A.y = fmaf((s), (W).y, A.y); \
    A.z = fmaf((s), (W).z, A.z); A.w = fmaf((s), (W).w, A.w);

// Row indexing: rows 0..127 = hf (b*8+h -> hboxes), 128..383 = of (b*16+o -> oboxes).

// K1: partial ROI row sums (R5 version — bisect-measured ~10.7us warm).
// grid (384, 15), 192 thr.  Block (row, q) sums box-row y1+q over x and
// writes the 768-ch partial to P[(row*15+q)*768..].  One contiguous 3KB
// span per wave-load -> max coalescing; early exit for dead stripes.
__global__ __launch_bounds__(192) void roi_rows_kernel(const float* __restrict__ feats,
                                                       const int* __restrict__ hboxes,
                                                       const int* __restrict__ oboxes,
                                                       float* __restrict__ P)
{
    int row = blockIdx.x;
    int q   = blockIdx.y;
    const int* box = (row < 128) ? (hboxes + row * 4) : (oboxes + (row - 128) * 4);
    int x1 = box[0], y1 = box[1], x2 = box[2], y2 = box[3];
    if (q >= y2 - y1) return;
    int b = (row < 128) ? (row >> 3) : ((row - 128) >> 4);
    int y = y1 + q;

    int t = threadIdx.x;
    const float4* rp = (const float4*)(feats + (size_t)((b * HH + y) * WW) * DD) + t;

    float4 a0 = make_float4(0.f, 0.f, 0.f, 0.f);
    float4 a1 = make_float4(0.f, 0.f, 0.f, 0.f);
    float4 a2 = make_float4(0.f, 0.f, 0.f, 0.f);
    float4 a3 = make_float4(0.f, 0.f, 0.f, 0.f);
    int x = x1;
    for (; x + 3 < x2; x += 4) {
        float4 v0 = rp[(size_t)(x + 0) * 192];
        float4 v1 = rp[(size_t)(x + 1) * 192];
        float4 v2 = rp[(size_t)(x + 2) * 192];
        float4 v3 = rp[(size_t)(x + 3) * 192];
        a0.x += v0.x; a0.y += v0.y; a0.z += v0.z; a0.w += v0.w;
        a1.x += v1.x; a1.y += v1.y; a1.z += v1.z; a1.w += v1.w;
        a2.x += v2.x; a2.y += v2.y; a2.z += v2.z; a2.w += v2.w;
        a3.x += v3.x; a3.y += v3.y; a3.z += v3.z; a3.w += v3.w;
    }
    for (; x < x2; ++x) {
        float4 v0 = rp[(size_t)x * 192];
        a0.x += v0.x; a0.y += v0.y; a0.z += v0.z; a0.w += v0.w;
    }
    a0.x += a1.x + a2.x + a3.x;
    a0.y += a1.y + a2.y + a3.y;
    a0.z += a1.z + a2.z + a3.z;
    a0.w += a1.w + a2.w + a3.w;
    ((float4*)(P + (size_t)(row * MAXBH + q) * DD))[t] = a0;
}

// K2: P-reduce staging + GEMM1 slice.  grid (96, 8), 512 thr.
// Block (bx, kq): rows r0=bx*4..+3, channels kq*96..+95.
// Staging: 384 slots (r,k), one per thread: reduce P over bh, scale.
// GEMM: R14 structure on 256 thr (c in 0..127, kh in 0..1 -> 48-k half).
// Only 17.5 KB LDS -> high occupancy.
__global__ __launch_bounds__(512) void gemm1_kernel(const float* __restrict__ P,
                                                    const int* __restrict__ hboxes,
                                                    const int* __restrict__ oboxes,
                                                    const float* __restrict__ W1,
                                                    float* __restrict__ AB)
{
    __shared__ __align__(16) float xs[4][KCH];        // 1.5 KB
    __shared__ __align__(16) float red[2][4][512];    // 16 KB
    int r0 = blockIdx.x * 4;
    int kq = blockIdx.y;
    int t = threadIdx.x;

    if (t < 4 * KCH) {
        int r = t / KCH;
        int k = t - r * KCH;
        int row = r0 + r;
        const int* box = (row < 128) ? (hboxes + row * 4) : (oboxes + (row - 128) * 4);
        int bh = box[3] - box[1];
        float inv_area = 1.0f / (float)(bh * (box[2] - box[0]));
        const float* Pp = P + (size_t)(row * MAXBH) * DD + kq * KCH + k;
        float s = 0.f;
        for (int yy = 0; yy < bh; ++yy) s += Pp[(size_t)yy * DD];
        xs[r][k] = s * inv_area;
    }
    __syncthreads();

    if (t < 256) {
        int c  = t & 127;
        int kh = t >> 7;
        int kb = kh * 48;
        const float* W1p = W1 + ((size_t)(((r0 < 128) ? 0 : DD) + kq * KCH + kb)) * 512 + 4 * c;

        float4 a[4];
#pragma unroll
        for (int r = 0; r < 4; ++r) a[r] = make_float4(0.f, 0.f, 0.f, 0.f);

        for (int kk = 0; kk < 48; kk += 8) {
            float4 w[8];
#pragma unroll
            for (int u = 0; u < 8; ++u) w[u] = *(const float4*)(W1p + (size_t)(kk + u) * 512);
#pragma unroll
            for (int r = 0; r < 4; ++r) {
                float4 x0 = *(const float4*)&xs[r][kb + kk];
                float4 x1 = *(const float4*)&xs[r][kb + kk + 4];
                float xv[8] = {x0.x, x0.y, x0.z, x0.w, x1.x, x1.y, x1.z, x1.w};
#pragma unroll
                for (int u = 0; u < 8; ++u) { FMA4(a[r], xv[u], w[u]); }
            }
        }
#pragma unroll
        for (int r = 0; r < 4; ++r) *(float4*)&red[kh][r][4 * c] = a[r];
    }
    __syncthreads();

    float* ABq = AB + (size_t)kq * ABSTRIDE;
    for (int idx = t; idx < 4 * 512; idx += 512) {
        int r = idx >> 9;
        int cc = idx & 511;
        ABq[(size_t)(r0 + r) * 512 + cc] = red[0][r][cc] + red[1][r][cc];
    }
}

// K3: fused pair-combine + layer2 + layer3 (R14 version, NKQ=8).
// 8 pair-rows/block, 1024 thr, grid 256.
__global__ __launch_bounds__(1024, 4) void mlp_kernel(const float* __restrict__ AB,
                                                      const float* __restrict__ b1,
                                                      const float* __restrict__ W2,
                                                      const float* __restrict__ b2,
                                                      const float* __restrict__ W3,
                                                      const float* __restrict__ b3,
                                                      float* __restrict__ out)
{
    __shared__ __align__(16) float h1[8][512];      // 16 KB
    __shared__ __align__(16) float red[8][8][256];  // 64 KB (reused by phase 3)
    __shared__ __align__(16) float h2[8][256];      // 8 KB
    int p0 = blockIdx.x * 8;
    int t = threadIdx.x;

    // phase 1: h1 = relu(A_row + B_row + b1).  1024 float4 slots, 1 per thread.
    {
        int r  = t >> 7;                            // pair-row 0..7
        int k4 = t & 127;                           // float4 index in 512
        int p = p0 + r;
        int rowA = p >> 4;                          // b*8 + h
        int rowB = 128 + (p >> 7) * 16 + (p & 15);  // 128 + b*16 + o
        float4 v = ((const float4*)b1)[k4];
#pragma unroll
        for (int q = 0; q < NKQ; ++q) {
            float4 av = ((const float4*)(AB + (size_t)q * ABSTRIDE + (size_t)rowA * 512))[k4];
            float4 bv = ((const float4*)(AB + (size_t)q * ABSTRIDE + (size_t)rowB * 512))[k4];
            v.x += av.x + bv.x; v.y += av.y + bv.y;
            v.z += av.z + bv.z; v.w += av.w + bv.w;
        }
        v.x = v.x > 0.f ? v.x : 0.f; v.y = v.y > 0.f ? v.y : 0.f;
        v.z = v.z > 0.f ? v.z : 0.f; v.w = v.w > 0.f ? v.w : 0.f;
        *(float4*)&h1[r][k4 * 4] = v;
    }
    __syncthreads();

    // phase 2 accumulate: thread (c 0..63, kq2 0..7, rh 0..1)
    {
        int c   = t & 63;
        int kq2 = (t >> 6) & 7;
        int rh  = t >> 9;
        int kbase = kq2 * 64;
        const float* W2p = W2 + (size_t)kbase * 256 + 4 * c;
        float4 a[4];
#pragma unroll
        for (int r = 0; r < 4; ++r) a[r] = make_float4(0.f, 0.f, 0.f, 0.f);

        for (int kk = 0; kk < 64; kk += 8) {
            float4 w[8];
#pragma unroll
            for (int u = 0; u < 8; ++u) w[u] = *(const float4*)(W2p + (size_t)(kk + u) * 256);
#pragma unroll
            for (int r = 0; r < 4; ++r) {
                float4 x0 = *(const float4*)&h1[rh * 4 + r][kbase + kk];
                float4 x1 = *(const float4*)&h1[rh * 4 + r][kbase + kk + 4];
                float xv[8] = {x0.x, x0.y, x0.z, x0.w, x1.x, x1.y, x1.z, x1.w};
#pragma unroll
                for (int u = 0; u < 8; ++u) { FMA4(a[r], xv[u], w[u]); }
            }
        }
#pragma unroll
        for (int r = 0; r < 4; ++r) *(float4*)&red[kq2][rh * 4 + r][4 * c] = a[r];
    }
    __syncthreads();

    // phase 2 reduce: h2[r][c] = relu(sum_kq2 red + b2)
    for (int idx = t; idx < 8 * 256; idx += 1024) {
        int r = idx >> 8;
        int cc = idx & 255;
        float s = b2[cc];
#pragma unroll
        for (int q = 0; q < 8; ++q) s += red[q][r][cc];
        h2[r][cc] = s > 0.f ? s : 0.f;
    }
    __syncthreads();

    // phase 3 accumulate: thread (o, jq): o in 0..116, j in [jq*32, +32)
    float* pr = &red[0][0][0];     // reuse: pr[(jq*8+r)*NREL + o], [8][8][117]
    if (t < 8 * NREL) {
        int o = t % NREL;
        int jq = t / NREL;
        float acc[8] = {};
        const float* W3p = W3 + o;
        for (int j = jq * 32; j < jq * 32 + 32; j += 8) {
            float w[8];
#pragma unroll
            for (int u = 0; u < 8; ++u) w[u] = W3p[(size_t)(j + u) * NREL];
#pragma unroll
            for (int r = 0; r < 8; ++r) {
                float4 x0 = *(const float4*)&h2[r][j];
                float4 x1 = *(const float4*)&h2[r][j + 4];
                acc[r] = fmaf(x0.x, w[0], acc[r]); acc[r] = fmaf(x0.y, w[1], acc[r]);
                acc[r] = fmaf(x0.z, w[2], acc[r]); acc[r] = fmaf(x0.w, w[3], acc[r]);
                acc[r] = fmaf(x1.x, w[4], acc[r]); acc[r] = fmaf(x1.y, w[5], acc[r]);
                acc[r] = fmaf(x1.z, w[6], acc[r]); acc[r] = fmaf(x1.w, w[7], acc[r]);
            }
        }
#pragma unroll
        for (int r = 0; r < 8; ++r) pr[(jq * 8 + r) * NREL + o] = acc[r];
    }
    __syncthreads();

    // phase 3 reduce: out[p0+r][o] = sum_jq pr + b3[o]
    if (t < 8 * NREL) {
        int r = t / NREL;
        int o = t - r * NREL;
        float s = b3[o];
#pragma unroll
        for (int q = 0; q < 8; ++q) s += pr[(q * 8 + r) * NREL + o];
        out[(size_t)(p0 + r) * NREL + o] = s;
    }
}

extern "C" void kernel_launch(void* const* d_in, const int* in_sizes, int n_in,
                              void* d_out, int out_size, void* d_ws, size_t ws_size,
                              hipStream_t stream) {
    const float* feats  = (const float*)d_in[0];
    const int*   hboxes = (const int*)d_in[1];
    const int*   oboxes = (const int*)d_in[2];
    const float* W1     = (const float*)d_in[3];
    const float* b1     = (const float*)d_in[4];
    const float* W2     = (const float*)d_in[5];
    const float* b2     = (const float*)d_in[6];
    const float* W3     = (const float*)d_in[7];
    const float* b3     = (const float*)d_in[8];
    float* out = (float*)d_out;

    float* P  = (float*)d_ws;                       // 384 x 15 x 768 partial row sums
    float* AB = P + (size_t)384 * MAXBH * DD;       // 8 x 384 x 512 kq partials

    roi_rows_kernel<<<dim3(384, MAXBH), dim3(192), 0, stream>>>(feats, hboxes, oboxes, P);
    gemm1_kernel<<<dim3(96, NKQ), dim3(512), 0, stream>>>(P, hboxes, oboxes, W1, AB);
    mlp_kernel<<<dim3(256), dim3(1024), 0, stream>>>(AB, b1, W2, b2, W3, b3, out);
}

// Round 21
// 43.648 us; speedup vs baseline: 1.3241x; 1.3241x over previous
//
#include <hip/hip_runtime.h>

#define BB   16
#define HH   74
#define WW   74
#define DD   768
#define NHh  8
#define NOo  16
#define NREL 117
#define NKQ  8
#define KCH  96                      // channels per kq slice
#define ABSTRIDE (384 * 512)

#define FMA4(A, s, W) \
    A.x = fmaf((s), (W).x, A.x); A.y = fmaf((s), (W).y, A.y); \
    A.z = fmaf((s), (W).z, A.z); A.w = fmaf((s), (W).w, A.w);

// Row indexing: rows 0..127 = hf (b*8+h -> hboxes), 128..383 = of (b*16+o -> oboxes).

// K12: fused ROI-mean + GEMM1 slice.  grid (96, 8), 512 thr.
// LDS 41 KB -> 3 blocks/CU (6 waves/SIMD) for HBM latency hiding.
// [R14 best-measured configuration: 44.0 us total]
__global__ __launch_bounds__(512, 6) void roi_gemm1_kernel(const float* __restrict__ feats,
                                                           const int* __restrict__ hboxes,
                                                           const int* __restrict__ oboxes,
                                                           const float* __restrict__ W1,
                                                           float* __restrict__ AB)
{
    __shared__ __align__(16) float part[15][4][KCH];  // 23 KB
    __shared__ __align__(16) float xs[4][KCH];        // 1.5 KB
    __shared__ __align__(16) float red[2][4][512];    // 16 KB
    int r0 = blockIdx.x * 4;
    int kq = blockIdx.y;
    int t = threadIdx.x;

    // stage 1a: one y-row per thread per box-row
    if (t < 360) {
        int c4 = t % 24;
        int s  = t / 24;               // stripe == y offset
        for (int r = 0; r < 4; ++r) {
            int row = r0 + r;
            const int* box = (row < 128) ? (hboxes + row * 4) : (oboxes + (row - 128) * 4);
            int x1 = box[0], y1 = box[1], x2 = box[2], y2 = box[3];
            if (s < y2 - y1) {
                int b = (row < 128) ? (row >> 3) : ((row - 128) >> 4);
                int y = y1 + s;
                const float4* rp = (const float4*)(feats + (size_t)((b * HH + y) * WW) * DD + kq * KCH) + c4;
                float4 a0 = make_float4(0.f, 0.f, 0.f, 0.f);
                float4 a1 = make_float4(0.f, 0.f, 0.f, 0.f);
                float4 a2 = make_float4(0.f, 0.f, 0.f, 0.f);
                float4 a3 = make_float4(0.f, 0.f, 0.f, 0.f);
                int x = x1;
                for (; x + 3 < x2; x += 4) {
                    float4 v0 = rp[(size_t)(x + 0) * 192];
                    float4 v1 = rp[(size_t)(x + 1) * 192];
                    float4 v2 = rp[(size_t)(x + 2) * 192];
                    float4 v3 = rp[(size_t)(x + 3) * 192];
                    a0.x += v0.x; a0.y += v0.y; a0.z += v0.z; a0.w += v0.w;
                    a1.x += v1.x; a1.y += v1.y; a1.z += v1.z; a1.w += v1.w;
                    a2.x += v2.x; a2.y += v2.y; a2.z += v2.z; a2.w += v2.w;
                    a3.x += v3.x; a3.y += v3.y; a3.z += v3.z; a3.w += v3.w;
                }
                for (; x < x2; ++x) {
                    float4 v0 = rp[(size_t)x * 192];
                    a0.x += v0.x; a0.y += v0.y; a0.z += v0.z; a0.w += v0.w;
                }
                a0.x += a1.x + a2.x + a3.x;
                a0.y += a1.y + a2.y + a3.y;
                a0.z += a1.z + a2.z + a3.z;
                a0.w += a1.w + a2.w + a3.w;
                *(float4*)&part[s][r][c4 * 4] = a0;
            }
        }
    }
    __syncthreads();

    // stage 1b: reduce live stripes -> xs, scale by inv_area
    for (int idx = t; idx < 4 * KCH; idx += 512) {
        int r = idx / KCH;
        int k = idx - r * KCH;
        int row = r0 + r;
        const int* box = (row < 128) ? (hboxes + row * 4) : (oboxes + (row - 128) * 4);
        int bh = box[3] - box[1];
        float inv_area = 1.0f / (float)(bh * (box[2] - box[0]));
        float ssum = 0.f;
        for (int s = 0; s < bh; ++s) ssum += part[s][r][k];
        xs[r][k] = ssum * inv_area;
    }
    __syncthreads();

    // stage 2: GEMM slice on 256 threads.  c = t&127 -> cols 4c..4c+3,
    // kh = t>>7 -> 48-k half of the 96-ch slice.
    if (t < 256) {
        int c  = t & 127;
        int kh = t >> 7;
        int kb = kh * 48;
        const float* W1p = W1 + ((size_t)(((r0 < 128) ? 0 : DD) + kq * KCH + kb)) * 512 + 4 * c;

        float4 a[4];
#pragma unroll
        for (int r = 0; r < 4; ++r) a[r] = make_float4(0.f, 0.f, 0.f, 0.f);

        for (int kk = 0; kk < 48; kk += 8) {
            float4 w[8];
#pragma unroll
            for (int u = 0; u < 8; ++u) w[u] = *(const float4*)(W1p + (size_t)(kk + u) * 512);
#pragma unroll
            for (int r = 0; r < 4; ++r) {
                float4 x0 = *(const float4*)&xs[r][kb + kk];
                float4 x1 = *(const float4*)&xs[r][kb + kk + 4];
                float xv[8] = {x0.x, x0.y, x0.z, x0.w, x1.x, x1.y, x1.z, x1.w};
#pragma unroll
                for (int u = 0; u < 8; ++u) { FMA4(a[r], xv[u], w[u]); }
            }
        }
#pragma unroll
        for (int r = 0; r < 4; ++r) *(float4*)&red[kh][r][4 * c] = a[r];
    }
    __syncthreads();

    float* ABq = AB + (size_t)kq * ABSTRIDE;
    for (int idx = t; idx < 4 * 512; idx += 512) {
        int r = idx >> 9;
        int cc = idx & 511;
        ABq[(size_t)(r0 + r) * 512 + cc] = red[0][r][cc] + red[1][r][cc];
    }
}

// K3: fused pair-combine + layer2 + layer3.  8 pair-rows/block, 1024 thr,
// grid 256.  Phase1 vectorized (float4 AB loads).  Phase2/3: 8 loads in flight.
__global__ __launch_bounds__(1024, 4) void mlp_kernel(const float* __restrict__ AB,
                                                      const float* __restrict__ b1,
                                                      const float* __restrict__ W2,
                                                      const float* __restrict__ b2,
                                                      const float* __restrict__ W3,
                                                      const float* __restrict__ b3,
                                                      float* __restrict__ out)
{
    __shared__ __align__(16) float h1[8][512];      // 16 KB
    __shared__ __align__(16) float red[8][8][256];  // 64 KB (reused by phase 3)
    __shared__ __align__(16) float h2[8][256];      // 8 KB
    int p0 = blockIdx.x * 8;
    int t = threadIdx.x;

    // phase 1: h1 = relu(A_row + B_row + b1).  1024 float4 slots, 1 per thread;
    // 16 independent float4 loads each.
    {
        int r  = t >> 7;                            // pair-row 0..7
        int k4 = t & 127;                           // float4 index in 512
        int p = p0 + r;
        int rowA = p >> 4;                          // b*8 + h
        int rowB = 128 + (p >> 7) * 16 + (p & 15);  // 128 + b*16 + o
        float4 v = ((const float4*)b1)[k4];
#pragma unroll
        for (int q = 0; q < NKQ; ++q) {
            float4 av = ((const float4*)(AB + (size_t)q * ABSTRIDE + (size_t)rowA * 512))[k4];
            float4 bv = ((const float4*)(AB + (size_t)q * ABSTRIDE + (size_t)rowB * 512))[k4];
            v.x += av.x + bv.x; v.y += av.y + bv.y;
            v.z += av.z + bv.z; v.w += av.w + bv.w;
        }
        v.x = v.x > 0.f ? v.x : 0.f; v.y = v.y > 0.f ? v.y : 0.f;
        v.z = v.z > 0.f ? v.z : 0.f; v.w = v.w > 0.f ? v.w : 0.f;
        *(float4*)&h1[r][k4 * 4] = v;
    }
    __syncthreads();

    // phase 2 accumulate: thread (c 0..63, kq2 0..7, rh 0..1)
    {
        int c   = t & 63;
        int kq2 = (t >> 6) & 7;
        int rh  = t >> 9;
        int kbase = kq2 * 64;
        const float* W2p = W2 + (size_t)kbase * 256 + 4 * c;
        float4 a[4];
#pragma unroll
        for (int r = 0; r < 4; ++r) a[r] = make_float4(0.f, 0.f, 0.f, 0.f);

        for (int kk = 0; kk < 64; kk += 8) {
            float4 w[8];
#pragma unroll
            for (int u = 0; u < 8; ++u) w[u] = *(const float4*)(W2p + (size_t)(kk + u) * 256);
#pragma unroll
            for (int r = 0; r < 4; ++r) {
                float4 x0 = *(const float4*)&h1[rh * 4 + r][kbase + kk];
                float4 x1 = *(const float4*)&h1[rh * 4 + r][kbase + kk + 4];
                float xv[8] = {x0.x, x0.y, x0.z, x0.w, x1.x, x1.y, x1.z, x1.w};
#pragma unroll
                for (int u = 0; u < 8; ++u) { FMA4(a[r], xv[u], w[u]); }
            }
        }
#pragma unroll
        for (int r = 0; r < 4; ++r) *(float4*)&red[kq2][rh * 4 + r][4 * c] = a[r];
    }
    __syncthreads();

    // phase 2 reduce: h2[r][c] = relu(sum_kq2 red + b2)
    for (int idx = t; idx < 8 * 256; idx += 1024) {
        int r = idx >> 8;
        int cc = idx & 255;
        float s = b2[cc];
#pragma unroll
        for (int q = 0; q < 8; ++q) s += red[q][r][cc];
        h2[r][cc] = s > 0.f ? s : 0.f;
    }
    __syncthreads();

    // phase 3 accumulate: thread (o, jq): o in 0..116, j in [jq*32, +32)
    float* pr = &red[0][0][0];     // reuse: pr[(jq*8+r)*NREL + o], [8][8][117]
    if (t < 8 * NREL) {
        int o = t % NREL;
        int jq = t / NREL;
        float acc[8] = {};
        const float* W3p = W3 + o;
        for (int j = jq * 32; j < jq * 32 + 32; j += 8) {
            float w[8];
#pragma unroll
            for (int u = 0; u < 8; ++u) w[u] = W3p[(size_t)(j + u) * NREL];
#pragma unroll
            for (int r = 0; r < 8; ++r) {
                float4 x0 = *(const float4*)&h2[r][j];
                float4 x1 = *(const float4*)&h2[r][j + 4];
                acc[r] = fmaf(x0.x, w[0], acc[r]); acc[r] = fmaf(x0.y, w[1], acc[r]);
                acc[r] = fmaf(x0.z, w[2], acc[r]); acc[r] = fmaf(x0.w, w[3], acc[r]);
                acc[r] = fmaf(x1.x, w[4], acc[r]); acc[r] = fmaf(x1.y, w[5], acc[r]);
                acc[r] = fmaf(x1.z, w[6], acc[r]); acc[r] = fmaf(x1.w, w[7], acc[r]);
            }
        }
#pragma unroll
        for (int r = 0; r < 8; ++r) pr[(jq * 8 + r) * NREL + o] = acc[r];
    }
    __syncthreads();

    // phase 3 reduce: out[p0+r][o] = sum_jq pr + b3[o]
    if (t < 8 * NREL) {
        int r = t / NREL;
        int o = t - r * NREL;
        float s = b3[o];
#pragma unroll
        for (int q = 0; q < 8; ++q) s += pr[(q * 8 + r) * NREL + o];
        out[(size_t)(p0 + r) * NREL + o] = s;
    }
}

extern "C" void kernel_launch(void* const* d_in, const int* in_sizes, int n_in,
                              void* d_out, int out_size, void* d_ws, size_t ws_size,
                              hipStream_t stream) {
    const float* feats  = (const float*)d_in[0];
    const int*   hboxes = (const int*)d_in[1];
    const int*   oboxes = (const int*)d_in[2];
    const float* W1     = (const float*)d_in[3];
    const float* b1     = (const float*)d_in[4];
    const float* W2     = (const float*)d_in[5];
    const float* b2     = (const float*)d_in[6];
    const float* W3     = (const float*)d_in[7];
    const float* b3     = (const float*)d_in[8];
    float* out = (float*)d_out;

    float* AB = (float*)d_ws;                       // 8 x 384 x 512 kq partials

    roi_gemm1_kernel<<<dim3(96, NKQ), dim3(512), 0, stream>>>(feats, hboxes, oboxes, W1, AB);
    mlp_kernel<<<dim3(256), dim3(1024), 0, stream>>>(AB, b1, W2, b2, W3, b3, out);
}